// Round 10
// baseline (773.929 us; speedup 1.0000x reference)
//
#include <hip/hip_runtime.h>
#include <hip/hip_bf16.h>

#define FEAT 256
#define NPB 512          // nodes per bin
#define NPB_SHIFT 9
#define MAXBINS 256
#define CAP 20480        // fixed bin capacity (mean ~16900, +28 sigma)
#define BIN_CHUNK 8192   // edges per phase-A block

typedef __attribute__((ext_vector_type(8))) short bf16x8;
typedef __attribute__((ext_vector_type(8))) ushort u16x8;
typedef __attribute__((ext_vector_type(4))) float f32x4;

__device__ __forceinline__ float bf2f(ushort h) {
    union { unsigned u; float f; } v; v.u = ((unsigned)h) << 16; return v.f;
}
__device__ __forceinline__ ushort f2bf(float f) {
    union { float f; unsigned u; } v; v.f = f;
    unsigned u = v.u;
    return (ushort)((u + 0x7FFFu + ((u >> 16) & 1u)) >> 16);
}

// ---------------- phase A: bin edges by dst into fixed-capacity bins ----------------

__global__ __launch_bounds__(256) void k_bin(const int* __restrict__ ei, int E, int N,
                                             int* __restrict__ bincur,
                                             int2* __restrict__ binbuf, int nbins) {
    __shared__ int hist[MAXBINS];
    __shared__ int base[MAXBINS];
    int t = threadIdx.x;
    int T = E + N;
    int start = blockIdx.x * BIN_CHUNK;
    int end = min(start + BIN_CHUNK, T);
    for (int b = t; b < nbins; b += 256) hist[b] = 0;
    __syncthreads();
    for (int idx = start + t; idx < end; idx += 256) {
        int d = (idx < E) ? ei[E + idx] : idx - E;
        atomicAdd(&hist[d >> NPB_SHIFT], 1);
    }
    __syncthreads();
    for (int b = t; b < nbins; b += 256) {
        int c = hist[b];
        base[b] = c ? (b * CAP + atomicAdd(&bincur[b], c)) : 0;
        hist[b] = 0;
    }
    __syncthreads();
    for (int idx = start + t; idx < end; idx += 256) {
        int s, d;
        if (idx < E) { s = ei[idx]; d = ei[E + idx]; }
        else         { s = idx - E; d = idx - E; }
        int b = d >> NPB_SHIFT;
        int local = atomicAdd(&hist[b], 1);
        binbuf[base[b] + local] = make_int2(s, d);
    }
}

// ---------- per-bin: in-block scan of bin sizes, histogram -> deg/dis/offs, CSR -------

__global__ __launch_bounds__(512) void k_histcsr(const int2* __restrict__ binbuf,
                                                 const int* __restrict__ bincur,
                                                 int* __restrict__ offs,
                                                 float* __restrict__ dis,
                                                 int* __restrict__ csr, int N, int nbins) {
    __shared__ int bsh[256];
    __shared__ int h[NPB];
    __shared__ int cur[NPB];
    int b = blockIdx.x;
    int t = threadIdx.x;
    int node0 = b * NPB;
    int nn = min(NPB, N - node0);
    // scan bin sizes (nbins <= 256) redundantly in every block
    if (t < 256) bsh[t] = (t < nbins) ? bincur[t] : 0;
    h[t] = 0; cur[t] = 0;
    __syncthreads();
    for (int d = 1; d < 256; d <<= 1) {
        int x = (t < 256 && t >= d) ? bsh[t - d] : 0;
        __syncthreads();
        if (t < 256) bsh[t] += x;
        __syncthreads();
    }
    int cnt = bincur[b];
    int bpre = bsh[b] - cnt;              // exclusive prefix of this bin
    if (b == 0 && t == 0) offs[N] = bsh[nbins - 1];
    int base = b * CAP;
    for (int i = t; i < cnt; i += 512) {
        atomicAdd(&h[binbuf[base + i].y - node0], 1);
    }
    __syncthreads();
    int v = h[t];
    for (int d = 1; d < 512; d <<= 1) {
        int x = (t >= d) ? h[t - d] : 0;
        __syncthreads();
        h[t] += x;
        __syncthreads();
    }
    int myoff = bpre + h[t] - v;          // global exclusive offset of node t
    if (t < nn) {
        offs[node0 + t] = myoff;
        dis[node0 + t] = rsqrtf((float)v);
    }
    h[t] = myoff;                         // repurpose as scatter base
    __syncthreads();
    for (int i = t; i < cnt; i += 512) {
        int2 e = binbuf[base + i];
        int ld = e.y - node0;
        int c = atomicAdd(&cur[ld], 1);
        csr[h[ld] + c] = e.x;
    }
}

// ---------------- fp32 -> bf16 pre-scaled table: y[r][f] = bf16(dis[r]*x[r][f]) --------

__global__ __launch_bounds__(256) void k_cvt(const float* __restrict__ x,
                                             ushort* __restrict__ y,
                                             const float* __restrict__ dis, int n4) {
    int i = blockIdx.x * blockDim.x + threadIdx.x;
    int stride = gridDim.x * blockDim.x;
    for (; i < n4; i += stride) {
        float d = dis[i >> 6];
        float4 v = ((const float4*)x)[i];
        ushort4 o;
        o.x = f2bf(v.x * d); o.y = f2bf(v.y * d);
        o.z = f2bf(v.z * d); o.w = f2bf(v.w * d);
        ((ushort4*)y)[i] = o;
    }
}

// ---------------- weight prep: transpose + bf16 (+ bnacc zero) ----------------

__global__ void k_wprep(const float* __restrict__ W1, const float* __restrict__ Wmu,
                        const float* __restrict__ Wls, const float* __restrict__ bmu,
                        const float* __restrict__ bls,
                        ushort* __restrict__ Wt1, ushort* __restrict__ Wtc,
                        float* __restrict__ biasc, float* __restrict__ bnacc) {
    int i = blockIdx.x * 256 + threadIdx.x;   // 0 .. 3*65536-1
    int m = i >> 16;
    int j = i & 65535;
    int n = j >> 8, k = j & 255;
    const float* W = (m == 0) ? W1 : (m == 1) ? Wmu : Wls;
    ushort v = f2bf(W[k * 256 + n]);
    if (m == 0) Wt1[j] = v;
    else if (m == 1) Wtc[j] = v;
    else Wtc[65536 + j] = v;
    if (i < 512) { biasc[i] = (i < 256) ? bmu[i] : bls[i - 256]; bnacc[i] = 0.f; }
}

// ---------------- aggregation: one wave per node, pre-scaled table --------------

__global__ __launch_bounds__(256) void k_agg(const ushort* __restrict__ in,
                                             ushort* __restrict__ out,
                                             const int* __restrict__ offs,
                                             const int* __restrict__ csr,
                                             const float* __restrict__ dis, int N) {
    int wid = blockIdx.x * 4 + ((int)threadIdx.x >> 6);
    if (wid >= N) return;
    int lane = threadIdx.x & 63;
    int half = lane >> 5;
    int l32 = lane & 31;
    int beg = offs[wid], end = offs[wid + 1];
    float acc[8] = {};
    int k = beg;
    for (; k + 16 <= end; k += 16) {
        int s0 = csr[k + half];
        int s1 = csr[k + 2 + half];
        int s2 = csr[k + 4 + half];
        int s3 = csr[k + 6 + half];
        int s4 = csr[k + 8 + half];
        int s5 = csr[k + 10 + half];
        int s6 = csr[k + 12 + half];
        int s7 = csr[k + 14 + half];
        bf16x8 v0 = *(const bf16x8*)(in + (size_t)s0 * FEAT + l32 * 8);
        bf16x8 v1 = *(const bf16x8*)(in + (size_t)s1 * FEAT + l32 * 8);
        bf16x8 v2 = *(const bf16x8*)(in + (size_t)s2 * FEAT + l32 * 8);
        bf16x8 v3 = *(const bf16x8*)(in + (size_t)s3 * FEAT + l32 * 8);
        bf16x8 v4 = *(const bf16x8*)(in + (size_t)s4 * FEAT + l32 * 8);
        bf16x8 v5 = *(const bf16x8*)(in + (size_t)s5 * FEAT + l32 * 8);
        bf16x8 v6 = *(const bf16x8*)(in + (size_t)s6 * FEAT + l32 * 8);
        bf16x8 v7 = *(const bf16x8*)(in + (size_t)s7 * FEAT + l32 * 8);
        #pragma unroll
        for (int j = 0; j < 8; ++j) {
            float t0 = bf2f((ushort)v0[j]) + bf2f((ushort)v1[j]);
            float t1 = bf2f((ushort)v2[j]) + bf2f((ushort)v3[j]);
            float t2 = bf2f((ushort)v4[j]) + bf2f((ushort)v5[j]);
            float t3 = bf2f((ushort)v6[j]) + bf2f((ushort)v7[j]);
            acc[j] += (t0 + t1) + (t2 + t3);
        }
    }
    for (; k + 2 <= end; k += 2) {
        int s = csr[k + half];
        bf16x8 v = *(const bf16x8*)(in + (size_t)s * FEAT + l32 * 8);
        #pragma unroll
        for (int j = 0; j < 8; ++j) acc[j] += bf2f((ushort)v[j]);
    }
    if (k < end && half == 0) {
        int s = csr[k];
        bf16x8 v = *(const bf16x8*)(in + (size_t)s * FEAT + l32 * 8);
        #pragma unroll
        for (int j = 0; j < 8; ++j) acc[j] += bf2f((ushort)v[j]);
    }
    #pragma unroll
    for (int j = 0; j < 8; ++j) acc[j] += __shfl_xor(acc[j], 32, 64);
    if (half == 0) {
        float d = dis[wid];
        u16x8 o;
        #pragma unroll
        for (int j = 0; j < 8; ++j) o[j] = f2bf(acc[j] * d);
        *(u16x8*)(out + (size_t)wid * FEAT + l32 * 8) = o;
    }
}

// ---------------- MFMA bf16 GEMM, full-width N (A read exactly once) ----------------
// C[M x NCOL] = A[M x 256] @ Bt[NCOL x 256]^T + bias.
// Block: 128 rows, full A-tile (128x256, 64 KB LDS) staged once; loop nh over
// 128-col groups, Bs[128][64] staged per kt. 4 waves in 2x2, 64x64 wave tiles.
// BF16OUT: bf16 out + BN stats; else fp32 NT stores, cols >= split -> C1.

template <int NCOL, bool BF16OUT>
__global__ __launch_bounds__(256) void k_gemm(const ushort* __restrict__ A,
                                              const ushort* __restrict__ Bt,
                                              const float* __restrict__ bias,
                                              float* __restrict__ C0,
                                              float* __restrict__ C1,
                                              ushort* __restrict__ Cb,
                                              float* __restrict__ bnacc,
                                              int M, int split) {
    __shared__ ushort At[128 * 256];   // 64 KB, chunk-swizzled per 8-group
    __shared__ ushort Bs[128 * 64];    // 16 KB
    int t = threadIdx.x;
    int lane = t & 63;
    int wave = t >> 6;
    int wr = wave >> 1, wc = wave & 1;
    int by = blockIdx.x;
    int lo = lane & 15, g = lane >> 4;

    // stage full A-tile once (swizzled)
    #pragma unroll
    for (int i = 0; i < 16; ++i) {
        int idx = t + i * 256;        // 0..4095
        int r = idx >> 5;             // 0..127
        int c = idx & 31;             // logical 16B chunk
        int gr = by * 128 + r;
        bf16x8 av = {};
        if (gr < M) av = *(const bf16x8*)(A + (size_t)gr * 256 + c * 8);
        int pc = (c & 24) | ((c & 7) ^ (r & 7));
        *(bf16x8*)(At + r * 256 + pc * 8) = av;
    }
    __syncthreads();

    constexpr int NH = NCOL / 128;
    for (int nh = 0; nh < NH; ++nh) {
        f32x4 acc[4][4] = {};
        for (int kt = 0; kt < 4; ++kt) {
            #pragma unroll
            for (int u = 0; u < 4; ++u) {
                int idx = t + u * 256;         // 0..1023
                int r = idx >> 3, c = idx & 7;
                int lc = c ^ (r & 7);
                bf16x8 bv = *(const bf16x8*)(Bt + (size_t)(nh * 128 + r) * 256 + kt * 64 + lc * 8);
                *(bf16x8*)(Bs + r * 64 + c * 8) = bv;
            }
            __syncthreads();
            #pragma unroll
            for (int h = 0; h < 2; ++h) {
                bf16x8 af[4], bfr[4];
                #pragma unroll
                for (int m = 0; m < 4; ++m) {
                    int r = wr * 64 + m * 16 + lo;
                    af[m] = *(const bf16x8*)(At + r * 256 + (kt * 8 + ((h * 4 + g) ^ (r & 7))) * 8);
                }
                #pragma unroll
                for (int n = 0; n < 4; ++n) {
                    int r = wc * 64 + n * 16 + lo;
                    bfr[n] = *(const bf16x8*)(Bs + r * 64 + ((h * 4 + g) ^ (r & 7)) * 8);
                }
                #pragma unroll
                for (int m = 0; m < 4; ++m)
                    #pragma unroll
                    for (int n = 0; n < 4; ++n)
                        acc[m][n] = __builtin_amdgcn_mfma_f32_16x16x32_bf16(
                            af[m], bfr[n], acc[m][n], 0, 0, 0);
            }
            __syncthreads();
        }
        // epilogue for this nh (global/regs only; next staging is barrier-guarded)
        #pragma unroll
        for (int n = 0; n < 4; ++n) {
            int gc = nh * 128 + wc * 64 + n * 16 + lo;
            float bb = bias[gc];
            float s = 0.f, q = 0.f;
            #pragma unroll
            for (int m = 0; m < 4; ++m) {
                f32x4 v = acc[m][n];
                #pragma unroll
                for (int r4 = 0; r4 < 4; ++r4) {
                    int grow = by * 128 + wr * 64 + m * 16 + g * 4 + r4;
                    if (grow < M) {
                        float val = v[r4] + bb;
                        if (BF16OUT) {
                            Cb[(size_t)grow * 256 + gc] = f2bf(val);
                            s += val; q += val * val;
                        } else {
                            float* Cp = C0; int cc = gc;
                            if (gc >= split) { Cp = C1; cc = gc - split; }
                            __builtin_nontemporal_store(val, &Cp[(size_t)grow * 256 + cc]);
                        }
                    }
                }
            }
            if (BF16OUT) {
                s += __shfl_xor(s, 16, 64); s += __shfl_xor(s, 32, 64);
                q += __shfl_xor(q, 16, 64); q += __shfl_xor(q, 32, 64);
                if (g == 0) {
                    atomicAdd(&bnacc[gc], s);
                    atomicAdd(&bnacc[256 + gc], q);
                }
            }
        }
    }
}

// ---------------- BN + ReLU + dis pre-scale ----------------

__global__ __launch_bounds__(256) void k_bnapply(const ushort* __restrict__ h,
                                                 ushort* __restrict__ o,
                                                 const float* __restrict__ acc,
                                                 const float* __restrict__ gamma,
                                                 const float* __restrict__ beta,
                                                 const float* __restrict__ dis, int Nn) {
    int c4 = (threadIdx.x & 63) * 4;
    int rof = (int)threadIdx.x >> 6;
    float inv = 1.0f / (float)Nn;
    float g[4], b[4];
    #pragma unroll
    for (int j = 0; j < 4; ++j) {
        float mean = acc[c4 + j] * inv;
        float var = acc[FEAT + c4 + j] * inv - mean * mean;
        float rs = rsqrtf(var + 1e-5f);
        g[j] = gamma[c4 + j] * rs;
        b[j] = beta[c4 + j] - mean * g[j];
    }
    for (int r = blockIdx.x * 4 + rof; r < Nn; r += gridDim.x * 4) {
        float d = dis[r];
        ushort4 v = *(const ushort4*)(h + (size_t)r * FEAT + c4);
        float o0 = bf2f(v.x) * g[0] + b[0], o1 = bf2f(v.y) * g[1] + b[1];
        float o2 = bf2f(v.z) * g[2] + b[2], o3 = bf2f(v.w) * g[3] + b[3];
        ushort4 ov;
        ov.x = f2bf((o0 > 0.f ? o0 : 0.f) * d);
        ov.y = f2bf((o1 > 0.f ? o1 : 0.f) * d);
        ov.z = f2bf((o2 > 0.f ? o2 : 0.f) * d);
        ov.w = f2bf((o3 > 0.f ? o3 : 0.f) * d);
        *(ushort4*)(o + (size_t)r * FEAT + c4) = ov;
    }
}

// ---------------- launch ----------------

extern "C" void kernel_launch(void* const* d_in, const int* in_sizes, int n_in,
                              void* d_out, int out_size, void* d_ws, size_t ws_size,
                              hipStream_t stream) {
    const float* x     = (const float*)d_in[0];
    const int*   ei    = (const int*)d_in[1];
    const float* W1    = (const float*)d_in[2];
    const float* b1    = (const float*)d_in[3];
    const float* Wmu   = (const float*)d_in[4];
    const float* bmu   = (const float*)d_in[5];
    const float* Wls   = (const float*)d_in[6];
    const float* bls   = (const float*)d_in[7];
    const float* gamma = (const float*)d_in[8];
    const float* beta  = (const float*)d_in[9];

    int N = in_sizes[0] / FEAT;     // 100000
    int E = in_sizes[1] / 2;        // 3200000
    int nbins = (N + NPB - 1) / NPB;    // 196
    int T = E + N;

    float* out = (float*)d_out;
    float* mu  = out;                           // lower half: final mu
    float* ls  = out + (size_t)N * FEAT;        // upper half: H1(bf16) scratch, final logstd
    ushort* xtab = (ushort*)mu;                 // bf16 x-table / h'-table in mu region
    ushort* H1b  = (ushort*)ls;                 // bf16 H1 in ls region

    char* p = (char*)d_ws;
    auto alloc = [&](size_t bytes) -> void* {
        void* r = (void*)p;
        p += (bytes + 255) & ~(size_t)255;
        return r;
    };
    ushort* Abuf  = (ushort*)alloc((size_t)N * FEAT * 2);        // 51.2 MB (agg output)
    int2*   binbuf= (int2*)  alloc((size_t)nbins * CAP * 8);     // 32.1 MB
    int*    csr   = (int*)   alloc((size_t)T * 4);               // 13.2 MB
    int*    offs  = (int*)   alloc((size_t)(N + 1) * 4);
    float*  dis   = (float*) alloc((size_t)N * 4);
    float*  bnacc = (float*) alloc(512 * 4);
    ushort* Wt1   = (ushort*)alloc(65536 * 2);
    ushort* Wtc   = (ushort*)alloc(131072 * 2);
    float*  biasc = (float*) alloc(512 * 4);
    int*    bincur= (int*)   alloc((size_t)nbins * 4);

    // 1. binned edge scatter (fixed-capacity bins)
    hipMemsetAsync(bincur, 0, (size_t)nbins * 4, stream);
    k_bin<<<(T + BIN_CHUNK - 1) / BIN_CHUNK, 256, 0, stream>>>(ei, E, N, bincur, binbuf, nbins);

    // 2. per-bin: scan sizes (in-block) + histogram + scatter -> offs/dis + CSR
    k_histcsr<<<nbins, 512, 0, stream>>>(binbuf, bincur, offs, dis, csr, N, nbins);

    // 3. weight prep (+bnacc zero) + x -> pre-scaled bf16 table (mu region)
    k_wprep<<<768, 256, 0, stream>>>(W1, Wmu, Wls, bmu, bls, Wt1, Wtc, biasc, bnacc);
    k_cvt<<<2048, 256, 0, stream>>>(x, xtab, dis, N * FEAT / 4);

    int gblocks = (N + 127) / 128;

    // 4. A1 = Agg(x')
    k_agg<<<(N + 3) / 4, 256, 0, stream>>>(xtab, Abuf, offs, csr, dis, N);

    // 5. H1 = A1 @ W1 + b1 -> bf16 in ls region, BN stats fused (A read once)
    k_gemm<256, true><<<gblocks, 256, 0, stream>>>(Abuf, Wt1, b1, nullptr, nullptr, H1b, bnacc, N, 256);

    // 6. BN + ReLU + dis pre-scale -> h' table (mu region)
    k_bnapply<<<2048, 256, 0, stream>>>(H1b, xtab, bnacc, gamma, beta, dis, N);

    // 7. A2 = Agg(h')
    k_agg<<<(N + 3) / 4, 256, 0, stream>>>(xtab, Abuf, offs, csr, dis, N);

    // 8. [mu | logstd] = A2 @ [Wmu | Wls] + [bmu | bls] (A read once)
    k_gemm<512, false><<<gblocks, 256, 0, stream>>>(Abuf, Wtc, biasc, mu, ls, nullptr, nullptr, N, 256);
}

// Round 11
// 748.072 us; speedup vs baseline: 1.0346x; 1.0346x over previous
//
#include <hip/hip_runtime.h>
#include <hip/hip_bf16.h>

#define FEAT 256
#define NPB 512          // nodes per bin
#define NPB_SHIFT 9
#define MAXBINS 256
#define CAP 20480        // fixed bin capacity (mean ~16900, +28 sigma)
#define BIN_CHUNK 8192   // edges per phase-A block

typedef __attribute__((ext_vector_type(8))) short bf16x8;
typedef __attribute__((ext_vector_type(8))) ushort u16x8;
typedef __attribute__((ext_vector_type(4))) float f32x4;

__device__ __forceinline__ float bf2f(ushort h) {
    union { unsigned u; float f; } v; v.u = ((unsigned)h) << 16; return v.f;
}
__device__ __forceinline__ ushort f2bf(float f) {
    union { float f; unsigned u; } v; v.f = f;
    unsigned u = v.u;
    return (ushort)((u + 0x7FFFu + ((u >> 16) & 1u)) >> 16);
}

// ---------------- phase A: bin edges by dst into fixed-capacity bins ----------------

__global__ __launch_bounds__(256) void k_bin(const int* __restrict__ ei, int E, int N,
                                             int* __restrict__ bincur,
                                             int2* __restrict__ binbuf, int nbins) {
    __shared__ int hist[MAXBINS];
    __shared__ int base[MAXBINS];
    int t = threadIdx.x;
    int T = E + N;
    int start = blockIdx.x * BIN_CHUNK;
    int end = min(start + BIN_CHUNK, T);
    for (int b = t; b < nbins; b += 256) hist[b] = 0;
    __syncthreads();
    for (int idx = start + t; idx < end; idx += 256) {
        int d = (idx < E) ? ei[E + idx] : idx - E;
        atomicAdd(&hist[d >> NPB_SHIFT], 1);
    }
    __syncthreads();
    for (int b = t; b < nbins; b += 256) {
        int c = hist[b];
        base[b] = c ? (b * CAP + atomicAdd(&bincur[b], c)) : 0;
        hist[b] = 0;
    }
    __syncthreads();
    for (int idx = start + t; idx < end; idx += 256) {
        int s, d;
        if (idx < E) { s = ei[idx]; d = ei[E + idx]; }
        else         { s = idx - E; d = idx - E; }
        int b = d >> NPB_SHIFT;
        int local = atomicAdd(&hist[b], 1);
        binbuf[base[b] + local] = make_int2(s, d);
    }
}

// ---------- per-bin: in-block scan of bin sizes, histogram -> deg/dis/offs, CSR -------

__global__ __launch_bounds__(512) void k_histcsr(const int2* __restrict__ binbuf,
                                                 const int* __restrict__ bincur,
                                                 int* __restrict__ offs,
                                                 float* __restrict__ dis,
                                                 int* __restrict__ csr, int N, int nbins) {
    __shared__ int bsh[256];
    __shared__ int h[NPB];
    __shared__ int cur[NPB];
    int b = blockIdx.x;
    int t = threadIdx.x;
    int node0 = b * NPB;
    int nn = min(NPB, N - node0);
    if (t < 256) bsh[t] = (t < nbins) ? bincur[t] : 0;
    h[t] = 0; cur[t] = 0;
    __syncthreads();
    for (int d = 1; d < 256; d <<= 1) {
        int x = (t < 256 && t >= d) ? bsh[t - d] : 0;
        __syncthreads();
        if (t < 256) bsh[t] += x;
        __syncthreads();
    }
    int cnt = bincur[b];
    int bpre = bsh[b] - cnt;              // exclusive prefix of this bin
    if (b == 0 && t == 0) offs[N] = bsh[nbins - 1];
    int base = b * CAP;
    for (int i = t; i < cnt; i += 512) {
        atomicAdd(&h[binbuf[base + i].y - node0], 1);
    }
    __syncthreads();
    int v = h[t];
    for (int d = 1; d < 512; d <<= 1) {
        int x = (t >= d) ? h[t - d] : 0;
        __syncthreads();
        h[t] += x;
        __syncthreads();
    }
    int myoff = bpre + h[t] - v;          // global exclusive offset of node t
    if (t < nn) {
        offs[node0 + t] = myoff;
        dis[node0 + t] = rsqrtf((float)v);
    }
    h[t] = myoff;                         // repurpose as scatter base
    __syncthreads();
    for (int i = t; i < cnt; i += 512) {
        int2 e = binbuf[base + i];
        int ld = e.y - node0;
        int c = atomicAdd(&cur[ld], 1);
        csr[h[ld] + c] = e.x;
    }
}

// ---------------- fp32 -> bf16 pre-scaled table: y[r][f] = bf16(dis[r]*x[r][f]) --------

__global__ __launch_bounds__(256) void k_cvt(const float* __restrict__ x,
                                             ushort* __restrict__ y,
                                             const float* __restrict__ dis, int n4) {
    int i = blockIdx.x * blockDim.x + threadIdx.x;
    int stride = gridDim.x * blockDim.x;
    for (; i < n4; i += stride) {
        float d = dis[i >> 6];
        float4 v = ((const float4*)x)[i];
        ushort4 o;
        o.x = f2bf(v.x * d); o.y = f2bf(v.y * d);
        o.z = f2bf(v.z * d); o.w = f2bf(v.w * d);
        ((ushort4*)y)[i] = o;
    }
}

// ---------------- weight prep: transpose + bf16 (+ bnacc zero) ----------------

__global__ void k_wprep(const float* __restrict__ W1, const float* __restrict__ Wmu,
                        const float* __restrict__ Wls, const float* __restrict__ bmu,
                        const float* __restrict__ bls,
                        ushort* __restrict__ Wt1, ushort* __restrict__ Wtc,
                        float* __restrict__ biasc, float* __restrict__ bnacc) {
    int i = blockIdx.x * 256 + threadIdx.x;   // 0 .. 3*65536-1
    int m = i >> 16;
    int j = i & 65535;
    int n = j >> 8, k = j & 255;
    const float* W = (m == 0) ? W1 : (m == 1) ? Wmu : Wls;
    ushort v = f2bf(W[k * 256 + n]);
    if (m == 0) Wt1[j] = v;
    else if (m == 1) Wtc[j] = v;
    else Wtc[65536 + j] = v;
    if (i < 512) { biasc[i] = (i < 256) ? bmu[i] : bls[i - 256]; bnacc[i] = 0.f; }
}

// ---------------- aggregation: one wave per node, pre-scaled table --------------

__global__ __launch_bounds__(256) void k_agg(const ushort* __restrict__ in,
                                             ushort* __restrict__ out,
                                             const int* __restrict__ offs,
                                             const int* __restrict__ csr,
                                             const float* __restrict__ dis, int N) {
    int wid = blockIdx.x * 4 + ((int)threadIdx.x >> 6);
    if (wid >= N) return;
    int lane = threadIdx.x & 63;
    int half = lane >> 5;
    int l32 = lane & 31;
    int beg = offs[wid], end = offs[wid + 1];
    float acc[8] = {};
    int k = beg;
    for (; k + 16 <= end; k += 16) {
        int s0 = csr[k + half];
        int s1 = csr[k + 2 + half];
        int s2 = csr[k + 4 + half];
        int s3 = csr[k + 6 + half];
        int s4 = csr[k + 8 + half];
        int s5 = csr[k + 10 + half];
        int s6 = csr[k + 12 + half];
        int s7 = csr[k + 14 + half];
        bf16x8 v0 = *(const bf16x8*)(in + (size_t)s0 * FEAT + l32 * 8);
        bf16x8 v1 = *(const bf16x8*)(in + (size_t)s1 * FEAT + l32 * 8);
        bf16x8 v2 = *(const bf16x8*)(in + (size_t)s2 * FEAT + l32 * 8);
        bf16x8 v3 = *(const bf16x8*)(in + (size_t)s3 * FEAT + l32 * 8);
        bf16x8 v4 = *(const bf16x8*)(in + (size_t)s4 * FEAT + l32 * 8);
        bf16x8 v5 = *(const bf16x8*)(in + (size_t)s5 * FEAT + l32 * 8);
        bf16x8 v6 = *(const bf16x8*)(in + (size_t)s6 * FEAT + l32 * 8);
        bf16x8 v7 = *(const bf16x8*)(in + (size_t)s7 * FEAT + l32 * 8);
        #pragma unroll
        for (int j = 0; j < 8; ++j) {
            float t0 = bf2f((ushort)v0[j]) + bf2f((ushort)v1[j]);
            float t1 = bf2f((ushort)v2[j]) + bf2f((ushort)v3[j]);
            float t2 = bf2f((ushort)v4[j]) + bf2f((ushort)v5[j]);
            float t3 = bf2f((ushort)v6[j]) + bf2f((ushort)v7[j]);
            acc[j] += (t0 + t1) + (t2 + t3);
        }
    }
    for (; k + 2 <= end; k += 2) {
        int s = csr[k + half];
        bf16x8 v = *(const bf16x8*)(in + (size_t)s * FEAT + l32 * 8);
        #pragma unroll
        for (int j = 0; j < 8; ++j) acc[j] += bf2f((ushort)v[j]);
    }
    if (k < end && half == 0) {
        int s = csr[k];
        bf16x8 v = *(const bf16x8*)(in + (size_t)s * FEAT + l32 * 8);
        #pragma unroll
        for (int j = 0; j < 8; ++j) acc[j] += bf2f((ushort)v[j]);
    }
    #pragma unroll
    for (int j = 0; j < 8; ++j) acc[j] += __shfl_xor(acc[j], 32, 64);
    if (half == 0) {
        float d = dis[wid];
        u16x8 o;
        #pragma unroll
        for (int j = 0; j < 8; ++j) o[j] = f2bf(acc[j] * d);
        *(u16x8*)(out + (size_t)wid * FEAT + l32 * 8) = o;
    }
}

// ---------------- MFMA bf16 GEMM: 128x256 block tile, 8 waves ----------------
// C[M x NCOL] = A[M x 256] @ Bt[NCOL x 256]^T + bias.  BK=64 staged As+Bs,
// XOR-swizzled 128-B rows; waves 2x4, 64x64 tiles. 48 KB LDS -> 3 blocks/CU.
// BF16OUT: bf16 out + fused BN stats; else fp32 NT stores, cols >= 256 -> C1.

template <int NCOL, bool BF16OUT>
__global__ __launch_bounds__(512) void k_gemm(const ushort* __restrict__ A,
                                              const ushort* __restrict__ Bt,
                                              const float* __restrict__ bias,
                                              float* __restrict__ C0,
                                              float* __restrict__ C1,
                                              ushort* __restrict__ Cb,
                                              float* __restrict__ bnacc,
                                              int M) {
    __shared__ ushort As[128 * 64];   // 16 KB
    __shared__ ushort Bs[256 * 64];   // 32 KB
    int t = threadIdx.x;
    int lane = t & 63;
    int wave = t >> 6;                 // 0..7
    int wr = wave >> 2, wc = wave & 3; // 2 x 4 wave grid
    int bx = blockIdx.x, by = blockIdx.y;
    int lo = lane & 15, g = lane >> 4;
    f32x4 acc[4][4] = {};
    int chunk = t & 7;
    int row8 = t >> 3;                 // 0..63

    for (int kt = 0; kt < 4; ++kt) {
        int k0 = kt * 64;
        #pragma unroll
        for (int i = 0; i < 2; ++i) {        // As: 128 rows
            int r = row8 + i * 64;
            int lc = chunk ^ (r & 7);
            int gr = by * 128 + r;
            bf16x8 av = {};
            if (gr < M) av = *(const bf16x8*)(A + (size_t)gr * 256 + k0 + lc * 8);
            *(bf16x8*)(As + r * 64 + chunk * 8) = av;
        }
        #pragma unroll
        for (int i = 0; i < 4; ++i) {        // Bs: 256 rows (output cols)
            int r = row8 + i * 64;
            int lc = chunk ^ (r & 7);
            int gn = bx * 256 + r;
            bf16x8 bv = *(const bf16x8*)(Bt + (size_t)gn * 256 + k0 + lc * 8);
            *(bf16x8*)(Bs + r * 64 + chunk * 8) = bv;
        }
        __syncthreads();
        #pragma unroll
        for (int h = 0; h < 2; ++h) {
            bf16x8 af[4], bfr[4];
            #pragma unroll
            for (int m = 0; m < 4; ++m) {
                int r = wr * 64 + m * 16 + lo;
                af[m] = *(const bf16x8*)(As + r * 64 + (((h * 4 + g) ^ (r & 7)) * 8));
            }
            #pragma unroll
            for (int n = 0; n < 4; ++n) {
                int r = wc * 64 + n * 16 + lo;
                bfr[n] = *(const bf16x8*)(Bs + r * 64 + (((h * 4 + g) ^ (r & 7)) * 8));
            }
            #pragma unroll
            for (int m = 0; m < 4; ++m)
                #pragma unroll
                for (int n = 0; n < 4; ++n)
                    acc[m][n] = __builtin_amdgcn_mfma_f32_16x16x32_bf16(
                        af[m], bfr[n], acc[m][n], 0, 0, 0);
        }
        __syncthreads();
    }
    #pragma unroll
    for (int n = 0; n < 4; ++n) {
        int gc = bx * 256 + wc * 64 + n * 16 + lo;
        float bb = bias[gc];
        float s = 0.f, q = 0.f;
        #pragma unroll
        for (int m = 0; m < 4; ++m) {
            f32x4 v = acc[m][n];
            #pragma unroll
            for (int r4 = 0; r4 < 4; ++r4) {
                int grow = by * 128 + wr * 64 + m * 16 + g * 4 + r4;
                if (grow < M) {
                    float val = v[r4] + bb;
                    if (BF16OUT) {
                        Cb[(size_t)grow * 256 + gc] = f2bf(val);
                        s += val; q += val * val;
                    } else {
                        float* Cp = C0; int cc = gc;
                        if (gc >= 256) { Cp = C1; cc = gc - 256; }
                        __builtin_nontemporal_store(val, &Cp[(size_t)grow * 256 + cc]);
                    }
                }
            }
        }
        if (BF16OUT) {
            s += __shfl_xor(s, 16, 64); s += __shfl_xor(s, 32, 64);
            q += __shfl_xor(q, 16, 64); q += __shfl_xor(q, 32, 64);
            if (g == 0) {
                atomicAdd(&bnacc[gc], s);
                atomicAdd(&bnacc[256 + gc], q);
            }
        }
    }
}

// ---------------- BN + ReLU + dis pre-scale ----------------

__global__ __launch_bounds__(256) void k_bnapply(const ushort* __restrict__ h,
                                                 ushort* __restrict__ o,
                                                 const float* __restrict__ acc,
                                                 const float* __restrict__ gamma,
                                                 const float* __restrict__ beta,
                                                 const float* __restrict__ dis, int Nn) {
    int c4 = (threadIdx.x & 63) * 4;
    int rof = (int)threadIdx.x >> 6;
    float inv = 1.0f / (float)Nn;
    float g[4], b[4];
    #pragma unroll
    for (int j = 0; j < 4; ++j) {
        float mean = acc[c4 + j] * inv;
        float var = acc[FEAT + c4 + j] * inv - mean * mean;
        float rs = rsqrtf(var + 1e-5f);
        g[j] = gamma[c4 + j] * rs;
        b[j] = beta[c4 + j] - mean * g[j];
    }
    for (int r = blockIdx.x * 4 + rof; r < Nn; r += gridDim.x * 4) {
        float d = dis[r];
        ushort4 v = *(const ushort4*)(h + (size_t)r * FEAT + c4);
        float o0 = bf2f(v.x) * g[0] + b[0], o1 = bf2f(v.y) * g[1] + b[1];
        float o2 = bf2f(v.z) * g[2] + b[2], o3 = bf2f(v.w) * g[3] + b[3];
        ushort4 ov;
        ov.x = f2bf((o0 > 0.f ? o0 : 0.f) * d);
        ov.y = f2bf((o1 > 0.f ? o1 : 0.f) * d);
        ov.z = f2bf((o2 > 0.f ? o2 : 0.f) * d);
        ov.w = f2bf((o3 > 0.f ? o3 : 0.f) * d);
        *(ushort4*)(o + (size_t)r * FEAT + c4) = ov;
    }
}

// ---------------- launch ----------------

extern "C" void kernel_launch(void* const* d_in, const int* in_sizes, int n_in,
                              void* d_out, int out_size, void* d_ws, size_t ws_size,
                              hipStream_t stream) {
    const float* x     = (const float*)d_in[0];
    const int*   ei    = (const int*)d_in[1];
    const float* W1    = (const float*)d_in[2];
    const float* b1    = (const float*)d_in[3];
    const float* Wmu   = (const float*)d_in[4];
    const float* bmu   = (const float*)d_in[5];
    const float* Wls   = (const float*)d_in[6];
    const float* bls   = (const float*)d_in[7];
    const float* gamma = (const float*)d_in[8];
    const float* beta  = (const float*)d_in[9];

    int N = in_sizes[0] / FEAT;     // 100000
    int E = in_sizes[1] / 2;        // 3200000
    int nbins = (N + NPB - 1) / NPB;    // 196
    int T = E + N;

    float* out = (float*)d_out;
    float* mu  = out;                           // lower half: final mu
    float* ls  = out + (size_t)N * FEAT;        // upper half: H1(bf16) scratch, final logstd
    ushort* xtab = (ushort*)mu;                 // bf16 x-table / h'-table in mu region
    ushort* H1b  = (ushort*)ls;                 // bf16 H1 in ls region

    char* p = (char*)d_ws;
    auto alloc = [&](size_t bytes) -> void* {
        void* r = (void*)p;
        p += (bytes + 255) & ~(size_t)255;
        return r;
    };
    ushort* Abuf  = (ushort*)alloc((size_t)N * FEAT * 2);        // 51.2 MB (agg output)
    int2*   binbuf= (int2*)  alloc((size_t)nbins * CAP * 8);     // 32.1 MB
    int*    csr   = (int*)   alloc((size_t)T * 4);               // 13.2 MB
    int*    offs  = (int*)   alloc((size_t)(N + 1) * 4);
    float*  dis   = (float*) alloc((size_t)N * 4);
    float*  bnacc = (float*) alloc(512 * 4);
    ushort* Wt1   = (ushort*)alloc(65536 * 2);
    ushort* Wtc   = (ushort*)alloc(131072 * 2);
    float*  biasc = (float*) alloc(512 * 4);
    int*    bincur= (int*)   alloc((size_t)nbins * 4);

    // 1. binned edge scatter (fixed-capacity bins)
    hipMemsetAsync(bincur, 0, (size_t)nbins * 4, stream);
    k_bin<<<(T + BIN_CHUNK - 1) / BIN_CHUNK, 256, 0, stream>>>(ei, E, N, bincur, binbuf, nbins);

    // 2. per-bin: scan sizes (in-block) + histogram + scatter -> offs/dis + CSR
    k_histcsr<<<nbins, 512, 0, stream>>>(binbuf, bincur, offs, dis, csr, N, nbins);

    // 3. weight prep (+bnacc zero) + x -> pre-scaled bf16 table (mu region)
    k_wprep<<<768, 256, 0, stream>>>(W1, Wmu, Wls, bmu, bls, Wt1, Wtc, biasc, bnacc);
    k_cvt<<<2048, 256, 0, stream>>>(x, xtab, dis, N * FEAT / 4);

    int gblocks = (N + 127) / 128;

    // 4. A1 = Agg(x')
    k_agg<<<(N + 3) / 4, 256, 0, stream>>>(xtab, Abuf, offs, csr, dis, N);

    // 5. H1 = A1 @ W1 + b1 -> bf16 in ls region, BN stats fused (A read once)
    dim3 g1(1, gblocks);
    k_gemm<256, true><<<g1, 512, 0, stream>>>(Abuf, Wt1, b1, nullptr, nullptr, H1b, bnacc, N);

    // 6. BN + ReLU + dis pre-scale -> h' table (mu region)
    k_bnapply<<<2048, 256, 0, stream>>>(H1b, xtab, bnacc, gamma, beta, dis, N);

    // 7. A2 = Agg(h')
    k_agg<<<(N + 3) / 4, 256, 0, stream>>>(xtab, Abuf, offs, csr, dis, N);

    // 8. [mu | logstd] = A2 @ [Wmu | Wls] + [bmu | bls] (A read 2x)
    dim3 g2(2, gblocks);
    k_gemm<512, false><<<g2, 512, 0, stream>>>(Abuf, Wtc, biasc, mu, ls, nullptr, nullptr, N);
}